// Round 1
// baseline (101.717 us; speedup 1.0000x reference)
//
#include <hip/hip_runtime.h>
#include <hip/hip_bf16.h>

#define Bn 64
#define Sn 1452
#define Dn 1024
#define Gn 288
#define Kn 4
#define Rn 32
#define MAXT 300

// ---------------- Kernel A: per-batch group validity, prefix scan, attention out ----------------
__global__ void __launch_bounds__(512)
phaseA_kernel(const int* __restrict__ idx,        // B*G*K
              const int* __restrict__ rem,        // B*R
              const int* __restrict__ attn,       // B*S
              int* __restrict__ cnt_ws,           // B*G
              int* __restrict__ gor_ws,           // B*G  (g_of_rank)
              int* __restrict__ nv_ws,            // B
              float* __restrict__ att_out,        // B*T (floats)
              int vis_end, int T) {
    const int b = blockIdx.x;
    const int tid = threadIdx.x;

    __shared__ int s_rem[Rn];
    __shared__ int s_scan[512];

    if (tid < Rn) {
        int r = rem[b * Rn + tid];
        s_rem[tid] = (r == -1) ? -2 : r;   // -2 never matches idx (idx >= -1)
    }
    __syncthreads();

    int valid = 0;
    if (tid < Gn) {
        int cnt = 0;
#pragma unroll
        for (int k = 0; k < Kn; ++k) {
            int v = idx[(b * Gn + tid) * Kn + k];
            bool m = (v != -1);
            if (m) {
#pragma unroll
                for (int r = 0; r < Rn; ++r) {
                    if (v == s_rem[r]) { m = false; }
                }
            }
            cnt += m ? 1 : 0;
        }
        cnt_ws[b * Gn + tid] = cnt;
        valid = (cnt > 0) ? 1 : 0;
    }

    s_scan[tid] = valid;
    __syncthreads();
    // Hillis-Steele inclusive scan over 512 entries
#pragma unroll
    for (int off = 1; off < 512; off <<= 1) {
        int mine = s_scan[tid];
        int add = (tid >= off) ? s_scan[tid - off] : 0;
        __syncthreads();
        s_scan[tid] = mine + add;
        __syncthreads();
    }
    const int nvalid = s_scan[511];

    if (tid < Gn && valid) {
        int rank = s_scan[tid] - 1;
        gor_ws[b * Gn + rank] = tid;
    }
    if (tid == 0) nv_ws[b] = nvalid;

    // attention output (written as float32, since d_out is read as one f32 buffer)
    for (int t = tid; t < T; t += 512) {
        float v;
        if (t < MAXT) {
            v = (t >= MAXT - nvalid) ? 1.0f : 0.0f;
        } else {
            v = (float)attn[b * Sn + vis_end + (t - MAXT)];
        }
        att_out[(size_t)b * T + t] = v;
    }
}

// ---------------- Kernel B: one block per output row ----------------
__global__ void __launch_bounds__(256)
phaseB_kernel(const float* __restrict__ hs,       // B*S*D
              const int* __restrict__ idx,        // B*G*K
              const int* __restrict__ pr,         // B*2
              const int* __restrict__ cnt_ws,
              const int* __restrict__ gor_ws,
              const int* __restrict__ nv_ws,
              float* __restrict__ out,            // B*T*D
              int vis_end, int T) {
    const int t = blockIdx.x;
    const int b = blockIdx.y;
    const int tid = threadIdx.x;   // 256 threads * float4 = 1024 floats

    float4* outp = (float4*)(out + ((size_t)b * T + t) * Dn);

    if (t >= MAXT) {
        // tail copy: hidden[b, vis_end + (t-MAXT), :]
        const float4* src = (const float4*)(hs + ((size_t)b * Sn + vis_end + (t - MAXT)) * Dn);
        outp[tid] = src[tid];
        return;
    }

    const int nvalid = nv_ws[b];
    if (t < MAXT - nvalid) {
        outp[tid] = make_float4(0.f, 0.f, 0.f, 0.f);
        return;
    }

    const int g = gor_ws[b * Gn + (t - (MAXT - nvalid))];
    const int start = pr[b * 2];
    const int L = pr[b * 2 + 1] - start + 1;

    float4 acc = make_float4(0.f, 0.f, 0.f, 0.f);
#pragma unroll
    for (int k = 0; k < Kn; ++k) {
        int v = idx[(b * Gn + g) * Kn + k];
        int w = (v >= 0) ? v : v + L;          // reference: idx_w = idx>=0 ? idx : idx+L
        const float4* row = (const float4*)(hs + ((size_t)b * Sn + start + w) * Dn);
        float4 r = row[tid];
        acc.x += r.x; acc.y += r.y; acc.z += r.z; acc.w += r.w;
    }
    const int c = cnt_ws[b * Gn + g];
    const float scale = 1.0f / (float)((c > 1) ? c : 1);
    acc.x *= scale; acc.y *= scale; acc.z *= scale; acc.w *= scale;
    outp[tid] = acc;
}

extern "C" void kernel_launch(void* const* d_in, const int* in_sizes, int n_in,
                              void* d_out, int out_size, void* d_ws, size_t ws_size,
                              hipStream_t stream) {
    const float* hs  = (const float*)d_in[0];  // hidden_states (B,S,D) f32
    const int* attn  = (const int*)d_in[1];    // attention_mask (B,S)
    const int* pr    = (const int*)d_in[2];    // patch_range_list (B,2)
    const int* idx   = (const int*)d_in[3];    // patch_indices_list_list (B,G,K)
    const int* rem   = (const int*)d_in[4];    // remove_index_list_list (B,R)

    float* out = (float*)d_out;

    // out_size = B*T*D + B*T  =>  T
    const int T = out_size / (Bn * (Dn + 1));
    const int vis_end = Sn - (T - MAXT);

    float* att_out = out + (size_t)Bn * T * Dn;

    // workspace layout
    int* cnt_ws = (int*)d_ws;                  // B*G
    int* gor_ws = cnt_ws + Bn * Gn;            // B*G
    int* nv_ws  = gor_ws + Bn * Gn;            // B

    phaseA_kernel<<<Bn, 512, 0, stream>>>(idx, rem, attn, cnt_ws, gor_ws, nv_ws,
                                          att_out, vis_end, T);
    phaseB_kernel<<<dim3(T, Bn), 256, 0, stream>>>(hs, idx, pr, cnt_ws, gor_ws, nv_ws,
                                                   out, vis_end, T);
}

// Round 2
// 95.048 us; speedup vs baseline: 1.0702x; 1.0702x over previous
//
#include <hip/hip_runtime.h>
#include <hip/hip_bf16.h>

#define Bn 64
#define Sn 1452
#define Dn 1024
#define Gn 288
#define Kn 4
#define Rn 32
#define MAXT 300

typedef float f32x4 __attribute__((ext_vector_type(4)));

// ---------------- Kernel A: per-batch group validity + ballot prefix scan ----------------
__global__ void __launch_bounds__(512)
phaseA_kernel(const int* __restrict__ idx,        // B*G*K
              const int* __restrict__ rem,        // B*R
              int* __restrict__ cnt_ws,           // B*G
              int* __restrict__ gor_ws,           // B*G  (g_of_rank)
              int* __restrict__ nv_ws) {          // B
    const int b = blockIdx.x;
    const int tid = threadIdx.x;

    __shared__ int s_rem[Rn];
    __shared__ int s_wsum[8];

    if (tid < Rn) {
        int r = rem[b * Rn + tid];
        s_rem[tid] = (r == -1) ? -2 : r;   // -2 never matches idx (idx >= -1)
    }
    __syncthreads();

    int cnt = 0;
    if (tid < Gn) {
#pragma unroll
        for (int k = 0; k < Kn; ++k) {
            int v = idx[(b * Gn + tid) * Kn + k];
            bool m = (v != -1);
            if (m) {
#pragma unroll
                for (int r = 0; r < Rn; ++r) {
                    if (v == s_rem[r]) { m = false; }
                }
            }
            cnt += m ? 1 : 0;
        }
        cnt_ws[b * Gn + tid] = cnt;
    }

    const int valid = (tid < Gn && cnt > 0) ? 1 : 0;
    const unsigned long long m = __ballot(valid);
    const int lane = tid & 63;
    const int w = tid >> 6;
    if (lane == 0) s_wsum[w] = __popcll(m);
    __syncthreads();

    int off = 0, tot = 0;
#pragma unroll
    for (int i = 0; i < 8; ++i) {
        int v = s_wsum[i];
        tot += v;
        if (i < w) off += v;
    }
    if (valid) {
        int rank = off + __popcll(m & ((1ull << lane) - 1ull));
        gor_ws[b * Gn + rank] = tid;
    }
    if (tid == 0) nv_ws[b] = tot;
}

// ---------------- Kernel B: one block per output row (+ its attention scalar) ----------------
__global__ void __launch_bounds__(256)
phaseB_kernel(const float* __restrict__ hs,       // B*S*D
              const int* __restrict__ idx,        // B*G*K
              const int* __restrict__ pr,         // B*2
              const int* __restrict__ attn,       // B*S
              const int* __restrict__ cnt_ws,
              const int* __restrict__ gor_ws,
              const int* __restrict__ nv_ws,
              float* __restrict__ out,            // B*T*D
              float* __restrict__ att_out,        // B*T
              int vis_end, int T) {
    const int t = blockIdx.x;
    const int b = blockIdx.y;
    const int tid = threadIdx.x;   // 256 threads * float4 = 1024 floats

    f32x4* outp = (f32x4*)(out + ((size_t)b * T + t) * Dn);

    if (t >= MAXT) {
        if (tid == 0)
            att_out[(size_t)b * T + t] = (float)attn[b * Sn + vis_end + (t - MAXT)];
        const f32x4* src = (const f32x4*)(hs + ((size_t)b * Sn + vis_end + (t - MAXT)) * Dn);
        __builtin_nontemporal_store(src[tid], &outp[tid]);
        return;
    }

    const int nvalid = nv_ws[b];
    if (tid == 0)
        att_out[(size_t)b * T + t] = (t >= MAXT - nvalid) ? 1.0f : 0.0f;

    if (t < MAXT - nvalid) {
        f32x4 z = {0.f, 0.f, 0.f, 0.f};
        __builtin_nontemporal_store(z, &outp[tid]);
        return;
    }

    const int g = gor_ws[b * Gn + (t - (MAXT - nvalid))];
    const int start = pr[b * 2];
    const int L = pr[b * 2 + 1] - start + 1;

    f32x4 acc = {0.f, 0.f, 0.f, 0.f};
#pragma unroll
    for (int k = 0; k < Kn; ++k) {
        int v = idx[(b * Gn + g) * Kn + k];
        int w = (v >= 0) ? v : v + L;          // reference: idx_w = idx>=0 ? idx : idx+L
        const f32x4* row = (const f32x4*)(hs + ((size_t)b * Sn + start + w) * Dn);
        acc += row[tid];
    }
    const int c = cnt_ws[b * Gn + g];
    const float scale = 1.0f / (float)((c > 1) ? c : 1);
    acc *= scale;
    __builtin_nontemporal_store(acc, &outp[tid]);
}

extern "C" void kernel_launch(void* const* d_in, const int* in_sizes, int n_in,
                              void* d_out, int out_size, void* d_ws, size_t ws_size,
                              hipStream_t stream) {
    const float* hs  = (const float*)d_in[0];  // hidden_states (B,S,D) f32
    const int* attn  = (const int*)d_in[1];    // attention_mask (B,S)
    const int* pr    = (const int*)d_in[2];    // patch_range_list (B,2)
    const int* idx   = (const int*)d_in[3];    // patch_indices_list_list (B,G,K)
    const int* rem   = (const int*)d_in[4];    // remove_index_list_list (B,R)

    float* out = (float*)d_out;

    // out_size = B*T*D + B*T  =>  T
    const int T = out_size / (Bn * (Dn + 1));
    const int vis_end = Sn - (T - MAXT);

    float* att_out = out + (size_t)Bn * T * Dn;

    // workspace layout
    int* cnt_ws = (int*)d_ws;                  // B*G
    int* gor_ws = cnt_ws + Bn * Gn;            // B*G
    int* nv_ws  = gor_ws + Bn * Gn;            // B

    phaseA_kernel<<<Bn, 512, 0, stream>>>(idx, rem, cnt_ws, gor_ws, nv_ws);
    phaseB_kernel<<<dim3(T, Bn), 256, 0, stream>>>(hs, idx, pr, attn,
                                                   cnt_ws, gor_ws, nv_ws,
                                                   out, att_out, vis_end, T);
}

// Round 3
// 89.011 us; speedup vs baseline: 1.1427x; 1.0678x over previous
//
#include <hip/hip_runtime.h>
#include <hip/hip_bf16.h>

#define Bn 64
#define Sn 1452
#define Dn 1024
#define Gn 288
#define Kn 4
#define Rn 32
#define MAXT 300

typedef float f32x4 __attribute__((ext_vector_type(4)));

// ---------------- Kernel A: validity, ballot scan, and ALL attention outputs ----------------
__global__ void __launch_bounds__(512)
phaseA_kernel(const int* __restrict__ idx,        // B*G*K
              const int* __restrict__ rem,        // B*R
              const int* __restrict__ attn,       // B*S
              int* __restrict__ cnt_ws,           // B*G
              int* __restrict__ gor_ws,           // B*G  (g_of_rank)
              int* __restrict__ nv_ws,            // B
              float* __restrict__ att_out,        // B*T
              int vis_end, int T) {
    const int b = blockIdx.x;
    const int tid = threadIdx.x;

    __shared__ int s_rem[Rn];
    __shared__ int s_wsum[8];

    if (tid < Rn) {
        int r = rem[b * Rn + tid];
        s_rem[tid] = (r == -1) ? -2 : r;   // -2 never matches idx (idx >= -1)
    }
    __syncthreads();

    int cnt = 0;
    if (tid < Gn) {
#pragma unroll
        for (int k = 0; k < Kn; ++k) {
            int v = idx[(b * Gn + tid) * Kn + k];
            bool m = (v != -1);
            if (m) {
#pragma unroll
                for (int r = 0; r < Rn; ++r) {
                    if (v == s_rem[r]) { m = false; }
                }
            }
            cnt += m ? 1 : 0;
        }
        cnt_ws[b * Gn + tid] = cnt;
    }

    const int valid = (tid < Gn && cnt > 0) ? 1 : 0;
    const unsigned long long m = __ballot(valid);
    const int lane = tid & 63;
    const int w = tid >> 6;
    if (lane == 0) s_wsum[w] = __popcll(m);
    __syncthreads();

    int off = 0, tot = 0;
#pragma unroll
    for (int i = 0; i < 8; ++i) {
        int v = s_wsum[i];
        tot += v;
        if (i < w) off += v;
    }
    if (valid) {
        int rank = off + __popcll(m & ((1ull << lane) - 1ull));
        gor_ws[b * Gn + rank] = tid;
    }
    if (tid == 0) nv_ws[b] = tot;

    const int nvalid = tot;   // uniform across block after ballot/ssum
    for (int t = tid; t < T; t += 512) {
        float v;
        if (t < MAXT) {
            v = (t >= MAXT - nvalid) ? 1.0f : 0.0f;
        } else {
            v = (float)attn[b * Sn + vis_end + (t - MAXT)];
        }
        att_out[(size_t)b * T + t] = v;
    }
}

// ---------------- Kernel B: head rows (gather-average), one block per row ----------------
__global__ void __launch_bounds__(256)
head_kernel(const float* __restrict__ hs,       // B*S*D
            const int* __restrict__ idx,        // B*G*K
            const int* __restrict__ pr,         // B*2
            const int* __restrict__ cnt_ws,
            const int* __restrict__ gor_ws,
            const int* __restrict__ nv_ws,
            float* __restrict__ out,            // B*T*D
            int T) {
    const int t = blockIdx.x;                   // 0..MAXT-1
    const int b = blockIdx.y;
    const int tid = threadIdx.x;                // 256 * f32x4 = 1024 floats

    f32x4* outp = (f32x4*)(out + ((size_t)b * T + t) * Dn);

    const int nvalid = nv_ws[b];
    if (t < MAXT - nvalid) {
        f32x4 z = {0.f, 0.f, 0.f, 0.f};
        __builtin_nontemporal_store(z, &outp[tid]);
        return;
    }

    const int g = gor_ws[b * Gn + (t - (MAXT - nvalid))];
    const int start = pr[b * 2];
    const int L = pr[b * 2 + 1] - start + 1;

    f32x4 acc = {0.f, 0.f, 0.f, 0.f};
#pragma unroll
    for (int k = 0; k < Kn; ++k) {
        int v = idx[(b * Gn + g) * Kn + k];
        int w = (v >= 0) ? v : v + L;          // reference: idx_w = idx>=0 ? idx : idx+L
        const f32x4* row = (const f32x4*)(hs + ((size_t)b * Sn + start + w) * Dn);
        acc += row[tid];
    }
    const int c = cnt_ws[b * Gn + g];
    const float scale = 1.0f / (float)((c > 1) ? c : 1);
    acc *= scale;
    __builtin_nontemporal_store(acc, &outp[tid]);
}

// ---------------- Kernel C: tail copy, 4 rows (16 KB) per block, 64 B/lane in flight ----------------
__global__ void __launch_bounds__(256)
tail_kernel(const float* __restrict__ hs,       // B*S*D
            float* __restrict__ out,            // B*T*D
            int vis_end, int T, int tail4) {    // tail4 = (T-MAXT)*Dn/4 f32x4 per batch
    const int c = blockIdx.x;                   // chunk of 4 rows
    const int b = blockIdx.y;
    const int tid = threadIdx.x;

    const f32x4* src = (const f32x4*)(hs + ((size_t)b * Sn + vis_end) * Dn);
    f32x4* dst = (f32x4*)(out + ((size_t)b * T + MAXT) * Dn);

    const int base = c * 1024;                  // 4 rows * 256 f32x4
    f32x4 v0, v1, v2, v3;
    int e0 = base + 0 * 256 + tid;
    int e1 = base + 1 * 256 + tid;
    int e2 = base + 2 * 256 + tid;
    int e3 = base + 3 * 256 + tid;
    bool p0 = e0 < tail4, p1 = e1 < tail4, p2 = e2 < tail4, p3 = e3 < tail4;
    if (p0) v0 = __builtin_nontemporal_load(&src[e0]);
    if (p1) v1 = __builtin_nontemporal_load(&src[e1]);
    if (p2) v2 = __builtin_nontemporal_load(&src[e2]);
    if (p3) v3 = __builtin_nontemporal_load(&src[e3]);
    if (p0) __builtin_nontemporal_store(v0, &dst[e0]);
    if (p1) __builtin_nontemporal_store(v1, &dst[e1]);
    if (p2) __builtin_nontemporal_store(v2, &dst[e2]);
    if (p3) __builtin_nontemporal_store(v3, &dst[e3]);
}

extern "C" void kernel_launch(void* const* d_in, const int* in_sizes, int n_in,
                              void* d_out, int out_size, void* d_ws, size_t ws_size,
                              hipStream_t stream) {
    const float* hs  = (const float*)d_in[0];  // hidden_states (B,S,D) f32
    const int* attn  = (const int*)d_in[1];    // attention_mask (B,S)
    const int* pr    = (const int*)d_in[2];    // patch_range_list (B,2)
    const int* idx   = (const int*)d_in[3];    // patch_indices_list_list (B,G,K)
    const int* rem   = (const int*)d_in[4];    // remove_index_list_list (B,R)

    float* out = (float*)d_out;

    // out_size = B*T*D + B*T  =>  T
    const int T = out_size / (Bn * (Dn + 1));
    const int vis_end = Sn - (T - MAXT);

    float* att_out = out + (size_t)Bn * T * Dn;

    // workspace layout
    int* cnt_ws = (int*)d_ws;                  // B*G
    int* gor_ws = cnt_ws + Bn * Gn;            // B*G
    int* nv_ws  = gor_ws + Bn * Gn;            // B

    const int tail_rows = T - MAXT;
    const int tail4 = tail_rows * (Dn / 4);
    const int nchunks = (tail_rows + 3) / 4;

    phaseA_kernel<<<Bn, 512, 0, stream>>>(idx, rem, attn, cnt_ws, gor_ws, nv_ws,
                                          att_out, vis_end, T);
    tail_kernel<<<dim3(nchunks, Bn), 256, 0, stream>>>(hs, out, vis_end, T, tail4);
    head_kernel<<<dim3(MAXT, Bn), 256, 0, stream>>>(hs, idx, pr, cnt_ws, gor_ws, nv_ws,
                                                    out, T);
}

// Round 4
// 83.050 us; speedup vs baseline: 1.2248x; 1.0718x over previous
//
#include <hip/hip_runtime.h>
#include <hip/hip_bf16.h>

#define Bn 64
#define Sn 1452
#define Dn 1024
#define Gn 288
#define Kn 4
#define Rn 32
#define MAXT 300

typedef float f32x4 __attribute__((ext_vector_type(4)));

// ---------------- Kernel A: validity, ballot scan, and ALL attention outputs ----------------
__global__ void __launch_bounds__(512)
phaseA_kernel(const int* __restrict__ idx,        // B*G*K
              const int* __restrict__ rem,        // B*R
              const int* __restrict__ attn,       // B*S
              int* __restrict__ cnt_ws,           // B*G
              int* __restrict__ gor_ws,           // B*G  (g_of_rank)
              int* __restrict__ nv_ws,            // B
              float* __restrict__ att_out,        // B*T
              int vis_end, int T) {
    const int b = blockIdx.x;
    const int tid = threadIdx.x;

    __shared__ int s_rem[Rn];
    __shared__ int s_wsum[8];

    if (tid < Rn) {
        int r = rem[b * Rn + tid];
        s_rem[tid] = (r == -1) ? -2 : r;   // -2 never matches idx (idx >= -1)
    }
    __syncthreads();

    int cnt = 0;
    if (tid < Gn) {
#pragma unroll
        for (int k = 0; k < Kn; ++k) {
            int v = idx[(b * Gn + tid) * Kn + k];
            bool m = (v != -1);
            if (m) {
#pragma unroll
                for (int r = 0; r < Rn; ++r) {
                    if (v == s_rem[r]) { m = false; }
                }
            }
            cnt += m ? 1 : 0;
        }
        cnt_ws[b * Gn + tid] = cnt;
    }

    const int valid = (tid < Gn && cnt > 0) ? 1 : 0;
    const unsigned long long m = __ballot(valid);
    const int lane = tid & 63;
    const int w = tid >> 6;
    if (lane == 0) s_wsum[w] = __popcll(m);
    __syncthreads();

    int off = 0, tot = 0;
#pragma unroll
    for (int i = 0; i < 8; ++i) {
        int v = s_wsum[i];
        tot += v;
        if (i < w) off += v;
    }
    if (valid) {
        int rank = off + __popcll(m & ((1ull << lane) - 1ull));
        gor_ws[b * Gn + rank] = tid;
    }
    if (tid == 0) nv_ws[b] = tot;

    const int nvalid = tot;
    for (int t = tid; t < T; t += 512) {
        float v;
        if (t < MAXT) {
            v = (t >= MAXT - nvalid) ? 1.0f : 0.0f;
        } else {
            v = (float)attn[b * Sn + vis_end + (t - MAXT)];
        }
        att_out[(size_t)b * T + t] = v;
    }
}

// ---------------- Fused rows kernel: head (2 rows/block) + tail (4 rows/block) ----------------
__global__ void __launch_bounds__(256)
rows_kernel(const float* __restrict__ hs,       // B*S*D
            const int* __restrict__ idx,        // B*G*K
            const int* __restrict__ pr,         // B*2
            const int* __restrict__ cnt_ws,
            const int* __restrict__ gor_ws,
            const int* __restrict__ nv_ws,
            float* __restrict__ out,            // B*T*D
            int vis_end, int T, int nheadblk, int tail4) {
    const int x = blockIdx.x;
    const int b = blockIdx.y;
    const int tid = threadIdx.x;

    if (x >= nheadblk) {
        // ---- tail: 4 rows (16 KB) per block, 64 B/lane in flight each way ----
        const int c = x - nheadblk;
        const f32x4* src = (const f32x4*)(hs + ((size_t)b * Sn + vis_end) * Dn);
        f32x4* dst = (f32x4*)(out + ((size_t)b * T + MAXT) * Dn);

        const int base = c * 1024;              // 4 rows * 256 f32x4
        f32x4 v0, v1, v2, v3;
        int e0 = base + 0 * 256 + tid;
        int e1 = base + 1 * 256 + tid;
        int e2 = base + 2 * 256 + tid;
        int e3 = base + 3 * 256 + tid;
        bool p0 = e0 < tail4, p1 = e1 < tail4, p2 = e2 < tail4, p3 = e3 < tail4;
        if (p0) v0 = __builtin_nontemporal_load(&src[e0]);
        if (p1) v1 = __builtin_nontemporal_load(&src[e1]);
        if (p2) v2 = __builtin_nontemporal_load(&src[e2]);
        if (p3) v3 = __builtin_nontemporal_load(&src[e3]);
        if (p0) __builtin_nontemporal_store(v0, &dst[e0]);
        if (p1) __builtin_nontemporal_store(v1, &dst[e1]);
        if (p2) __builtin_nontemporal_store(v2, &dst[e2]);
        if (p3) __builtin_nontemporal_store(v3, &dst[e3]);
        return;
    }

    // ---- head: rows 2x and 2x+1 ----
    const int nvalid = nv_ws[b];
    const int zcut = MAXT - nvalid;
    const int start = pr[b * 2];
    const int L = pr[b * 2 + 1] - start + 1;

#pragma unroll
    for (int i = 0; i < 2; ++i) {
        const int t = 2 * x + i;
        if (t >= MAXT) break;
        f32x4* outp = (f32x4*)(out + ((size_t)b * T + t) * Dn);
        if (t < zcut) {
            f32x4 z = {0.f, 0.f, 0.f, 0.f};
            __builtin_nontemporal_store(z, &outp[tid]);
            continue;
        }
        const int g = gor_ws[b * Gn + (t - zcut)];
        f32x4 acc = {0.f, 0.f, 0.f, 0.f};
#pragma unroll
        for (int k = 0; k < Kn; ++k) {
            int v = idx[(b * Gn + g) * Kn + k];
            int w = (v >= 0) ? v : v + L;      // reference: idx_w = idx>=0 ? idx : idx+L
            const f32x4* row = (const f32x4*)(hs + ((size_t)b * Sn + start + w) * Dn);
            acc += row[tid];
        }
        const int c = cnt_ws[b * Gn + g];
        const float scale = 1.0f / (float)((c > 1) ? c : 1);
        acc *= scale;
        __builtin_nontemporal_store(acc, &outp[tid]);
    }
}

extern "C" void kernel_launch(void* const* d_in, const int* in_sizes, int n_in,
                              void* d_out, int out_size, void* d_ws, size_t ws_size,
                              hipStream_t stream) {
    const float* hs  = (const float*)d_in[0];  // hidden_states (B,S,D) f32
    const int* attn  = (const int*)d_in[1];    // attention_mask (B,S)
    const int* pr    = (const int*)d_in[2];    // patch_range_list (B,2)
    const int* idx   = (const int*)d_in[3];    // patch_indices_list_list (B,G,K)
    const int* rem   = (const int*)d_in[4];    // remove_index_list_list (B,R)

    float* out = (float*)d_out;

    // out_size = B*T*D + B*T  =>  T
    const int T = out_size / (Bn * (Dn + 1));
    const int vis_end = Sn - (T - MAXT);

    float* att_out = out + (size_t)Bn * T * Dn;

    // workspace layout
    int* cnt_ws = (int*)d_ws;                  // B*G
    int* gor_ws = cnt_ws + Bn * Gn;            // B*G
    int* nv_ws  = gor_ws + Bn * Gn;            // B

    const int tail_rows = T - MAXT;
    const int tail4 = tail_rows * (Dn / 4);
    const int ntail = (tail_rows + 3) / 4;     // 4-row chunks
    const int nheadblk = (MAXT + 1) / 2;       // 2 rows per block

    phaseA_kernel<<<Bn, 512, 0, stream>>>(idx, rem, attn, cnt_ws, gor_ws, nv_ws,
                                          att_out, vis_end, T);
    rows_kernel<<<dim3(nheadblk + ntail, Bn), 256, 0, stream>>>(
        hs, idx, pr, cnt_ws, gor_ws, nv_ws, out, vis_end, T, nheadblk, tail4);
}

// Round 6
// 79.543 us; speedup vs baseline: 1.2788x; 1.0441x over previous
//
#include <hip/hip_runtime.h>
#include <hip/hip_bf16.h>

#define Bn 64
#define Sn 1452
#define Dn 1024
#define Gn 288
#define Kn 4
#define Rn 32
#define MAXT 300

typedef float f32x4 __attribute__((ext_vector_type(4)));

// One kernel does everything.
//  - head blocks (x < nheadblk): recompute the per-batch validity scan in-block
//    (idx/rem are L2-hot, ~4.7 KB per batch), then gather-average 2 rows + att.
//  - tail blocks: pure streaming copy of 4 rows + att scalars. No dependencies.
__global__ void __launch_bounds__(256)
fused2_kernel(const float* __restrict__ hs,       // B*S*D
              const int* __restrict__ idx,        // B*G*K
              const int* __restrict__ pr,         // B*2
              const int* __restrict__ rem,        // B*R
              const int* __restrict__ attn,       // B*S
              float* __restrict__ out,            // B*T*D
              float* __restrict__ att_out,        // B*T
              int vis_end, int T, int nheadblk, int tail4, int tailrows) {
    const int x = blockIdx.x;
    const int b = blockIdx.y;
    const int tid = threadIdx.x;

    if (x >= nheadblk) {
        // ---- tail: 4 rows (16 KB) per block ----
        const int c = x - nheadblk;
        if (tid < 4) {
            int tr = c * 4 + tid;
            if (tr < tailrows)
                att_out[(size_t)b * T + MAXT + tr] = (float)attn[b * Sn + vis_end + tr];
        }
        const f32x4* src = (const f32x4*)(hs + ((size_t)b * Sn + vis_end) * Dn);
        f32x4* dst = (f32x4*)(out + ((size_t)b * T + MAXT) * Dn);
        const int base = c * 1024;              // 4 rows * 256 f32x4
        f32x4 v0, v1, v2, v3;
        int e0 = base + 0 * 256 + tid;
        int e1 = base + 1 * 256 + tid;
        int e2 = base + 2 * 256 + tid;
        int e3 = base + 3 * 256 + tid;
        bool p0 = e0 < tail4, p1 = e1 < tail4, p2 = e2 < tail4, p3 = e3 < tail4;
        if (p0) v0 = __builtin_nontemporal_load(&src[e0]);
        if (p1) v1 = __builtin_nontemporal_load(&src[e1]);
        if (p2) v2 = __builtin_nontemporal_load(&src[e2]);
        if (p3) v3 = __builtin_nontemporal_load(&src[e3]);
        if (p0) __builtin_nontemporal_store(v0, &dst[e0]);
        if (p1) __builtin_nontemporal_store(v1, &dst[e1]);
        if (p2) __builtin_nontemporal_store(v2, &dst[e2]);
        if (p3) __builtin_nontemporal_store(v3, &dst[e3]);
        return;
    }

    // ---- head: in-block validity scan over 288 groups, then 2 gather rows ----
    __shared__ int s_rem[Rn];
    __shared__ unsigned long long s_mask[5];
    __shared__ int s_wsum[5];
    __shared__ short s_gor[Gn];
    __shared__ char s_cnt[Gn];

    const int lane = tid & 63;
    const int w = tid >> 6;

    if (tid < Rn) {
        int r = rem[b * Rn + tid];
        s_rem[tid] = (r == -1) ? -2 : r;       // -2 never matches idx (idx >= -1)
    }
    __syncthreads();

    // validity counts: group tid, and group 256+tid for tid<32
    int cnt1 = 0;
    {
        const int g = tid;
#pragma unroll
        for (int k = 0; k < Kn; ++k) {
            int v = idx[(b * Gn + g) * Kn + k];
            bool m = (v != -1);
#pragma unroll
            for (int r = 0; r < Rn; ++r) m = m && (v != s_rem[r]);
            cnt1 += m ? 1 : 0;
        }
        s_cnt[g] = (char)cnt1;
    }
    int cnt2 = 0;
    if (tid < Gn - 256) {
        const int g = 256 + tid;
#pragma unroll
        for (int k = 0; k < Kn; ++k) {
            int v = idx[(b * Gn + g) * Kn + k];
            bool m = (v != -1);
#pragma unroll
            for (int r = 0; r < Rn; ++r) m = m && (v != s_rem[r]);
            cnt2 += m ? 1 : 0;
        }
        s_cnt[g] = (char)cnt2;
    }

    unsigned long long m1 = __ballot(cnt1 > 0);
    if (lane == 0) { s_mask[w] = m1; s_wsum[w] = __popcll(m1); }
    if (w == 0) {
        unsigned long long m2 = __ballot(tid < Gn - 256 && cnt2 > 0);
        if (lane == 0) { s_mask[4] = m2; s_wsum[4] = __popcll(m2); }
    }
    __syncthreads();

    int pre[5], acc = 0;
#pragma unroll
    for (int i = 0; i < 5; ++i) { pre[i] = acc; acc += s_wsum[i]; }
    const int nvalid = acc;
    const int zcut = MAXT - nvalid;

    if (cnt1 > 0) {
        int rank = pre[w] + __popcll(s_mask[w] & ((1ull << lane) - 1ull));
        s_gor[rank] = (short)tid;
    }
    if (tid < Gn - 256 && cnt2 > 0) {
        int rank = pre[4] + __popcll(s_mask[4] & ((1ull << lane) - 1ull));
        s_gor[rank] = (short)(256 + tid);
    }
    __syncthreads();

    if (tid < 2) {
        int t = 2 * x + tid;
        att_out[(size_t)b * T + t] = (t >= zcut) ? 1.0f : 0.0f;
    }

    const int start = pr[b * 2];
    const int L = pr[b * 2 + 1] - start + 1;

#pragma unroll
    for (int i = 0; i < 2; ++i) {
        const int t = 2 * x + i;
        f32x4* outp = (f32x4*)(out + ((size_t)b * T + t) * Dn);
        if (t < zcut) {
            f32x4 z = {0.f, 0.f, 0.f, 0.f};
            __builtin_nontemporal_store(z, &outp[tid]);
            continue;
        }
        const int g = s_gor[t - zcut];
        f32x4 a = {0.f, 0.f, 0.f, 0.f};
#pragma unroll
        for (int k = 0; k < Kn; ++k) {
            int v = idx[(b * Gn + g) * Kn + k];
            int wi = (v >= 0) ? v : v + L;     // reference: idx_w = idx>=0 ? idx : idx+L
            const f32x4* row = (const f32x4*)(hs + ((size_t)b * Sn + start + wi) * Dn);
            a += row[tid];
        }
        const int c = (int)s_cnt[g];
        const float scale = 1.0f / (float)((c > 1) ? c : 1);
        a *= scale;
        __builtin_nontemporal_store(a, &outp[tid]);
    }
}

extern "C" void kernel_launch(void* const* d_in, const int* in_sizes, int n_in,
                              void* d_out, int out_size, void* d_ws, size_t ws_size,
                              hipStream_t stream) {
    const float* hs  = (const float*)d_in[0];  // hidden_states (B,S,D) f32
    const int* attn  = (const int*)d_in[1];    // attention_mask (B,S)
    const int* pr    = (const int*)d_in[2];    // patch_range_list (B,2)
    const int* idx   = (const int*)d_in[3];    // patch_indices_list_list (B,G,K)
    const int* rem   = (const int*)d_in[4];    // remove_index_list_list (B,R)

    float* out = (float*)d_out;

    // out_size = B*T*D + B*T  =>  T
    const int T = out_size / (Bn * (Dn + 1));
    const int vis_end = Sn - (T - MAXT);

    float* att_out = out + (size_t)Bn * T * Dn;

    const int tailrows = T - MAXT;
    const int tail4 = tailrows * (Dn / 4);
    const int ntail = (tailrows + 3) / 4;      // 4-row chunks
    const int nheadblk = (MAXT + 1) / 2;       // 2 rows per block

    fused2_kernel<<<dim3(nheadblk + ntail, Bn), 256, 0, stream>>>(
        hs, idx, pr, rem, attn, out, att_out, vis_end, T, nheadblk, tail4, tailrows);
}